// Round 20
// baseline (489.719 us; speedup 1.0000x reference)
//
#include <hip/hip_runtime.h>
#include <hip/hip_bf16.h>

// ---- types ----
typedef __bf16 bf16x8 __attribute__((ext_vector_type(8), may_alias));
typedef float f32x4 __attribute__((ext_vector_type(4), may_alias));
typedef unsigned short ushort_a __attribute__((may_alias));
typedef unsigned int uint_a __attribute__((may_alias));
typedef unsigned short us8 __attribute__((ext_vector_type(8), may_alias));

#define MFMA(a, b, c) __builtin_amdgcn_mfma_f32_16x16x32_bf16(a, b, c, 0, 0, 0)

__device__ __forceinline__ unsigned short f2bf(float f) {
  return __builtin_bit_cast(unsigned short, (__bf16)f);
}
__device__ __forceinline__ float bf2f(unsigned short u) {
  unsigned v = ((unsigned)u) << 16;
  return __builtin_bit_cast(float, v);
}

// Counted-vmcnt barrier (T4): publish own LDS ops, sync, leave global
// prefetch loads in flight (no vmcnt(0) drain).
__device__ __forceinline__ void kbar() {
  __builtin_amdgcn_sched_barrier(0);
  asm volatile("s_waitcnt lgkmcnt(0)" ::: "memory");
  __builtin_amdgcn_sched_barrier(0);
  __builtin_amdgcn_s_barrier();
  __builtin_amdgcn_sched_barrier(0);
}

// async global->LDS, 16B per lane; dest = wave-uniform base + lane*16
#define GLOAD(G, L)                                                          \
  __builtin_amdgcn_global_load_lds(                                          \
      (const __attribute__((address_space(1))) unsigned int*)(G),            \
      (__attribute__((address_space(3))) unsigned int*)(L), 16, 0, 0)

// ws layout (ushort elements):
//   wfB  [2304][384] @ 0
//   wgB  [128][384]  @ 884736    (rows >=12 zero)
//   waoB [384][384]  @ 933888
//   wfoB [384][1536] @ 1081344
//   xg   [65536][384]  @ 1671168
//   fused[65536][2304] @ 26836992  (q | kv | StarReLU(ff)); q overwritten by x_attn
//   gate [65536][16]   @ 177831936
#define OFF_WG 884736
#define OFF_WAO 933888
#define OFF_WFO 1081344
#define OFF_XG 1671168
#define OFF_FUSED 26836992
#define OFF_GATE 177831936

__global__ __launch_bounds__(256) void prep_weights(
    const float* __restrict__ wf, const float* __restrict__ wg,
    const float* __restrict__ wao, const float* __restrict__ wfo,
    unsigned short* __restrict__ ws) {
  int i = blockIdx.x * 256 + threadIdx.x;
  if (i < 884736) { ws[i] = f2bf(wf[i]); return; }
  int j = i - 884736;
  if (j < 49152) { ws[i] = f2bf(j < 4608 ? wg[j] : 0.0f); return; }
  j -= 49152;
  if (j < 147456) { ws[i] = f2bf(wao[j]); return; }
  j -= 147456;
  if (j < 589824) ws[i] = f2bf(wfo[j]);
}

// ---- k0: gather NCHW fp32 -> token-major bf16 xg [65536][384] ----
__global__ __launch_bounds__(256) void k0_gather(const float* __restrict__ x,
                                                 unsigned short* __restrict__ xg) {
  __shared__ __align__(16) char As[49152];
  int tid = threadIdx.x, wi = blockIdx.x;
  int b = wi >> 6, ghi = (wi >> 3) & 7, gwi = wi & 7;
  const float* xb = x + (size_t)b * 1572864 + (ghi * 8) * 64 + gwi * 8;
  for (int it = 0; it < 12; ++it) {
    int idx = it * 256 + tid;  // (c, p1)
    int c = idx % 384, p1 = idx / 384;
    const float* src = xb + (size_t)c * 4096 + p1 * 64;
    float4 v0 = *(const float4*)src, v1 = *(const float4*)(src + 4);
    float f[8] = {v0.x, v0.y, v0.z, v0.w, v1.x, v1.y, v1.z, v1.w};
#pragma unroll
    for (int jj = 0; jj < 8; ++jj) {
      int row = p1 * 8 + jj;
      int byte = (row * 768 + c * 2) ^ ((row & 7) << 4);
      *(ushort_a*)(As + byte) = f2bf(f[jj]);
    }
  }
  __syncthreads();
  unsigned short* og = xg + (size_t)wi * 24576;
#pragma unroll
  for (int it = 0; it < 12; ++it) {
    int idx = it * 256 + tid;
    int row = idx / 48, c = idx % 48;
    int byte = (row * 768 + c * 16) ^ ((row & 7) << 4);
    *(us8*)(og + (size_t)row * 384 + c * 8) = *(us8*)(As + byte);
  }
}

// ---- k1: fused = xg . W_fused^T  (M=65536, N=2304 + gate 16, K=384) ----
// gload_lds double-buffer + counted vmcnt(4) (r16/k3 template). A is
// L3-resident (33 MB fetch measured) so the 1-step pipeline covers latency;
// removing reg-staging kills the VALU bottleneck (39% VALUBusy in r19).
__global__ __launch_bounds__(512, 2) void k1_gemm(unsigned short* __restrict__ ws,
                                                  const float* __restrict__ srs,
                                                  const float* __restrict__ srb) {
  __shared__ __align__(1024) char sm[65536];  // A: 0/16384; B: 32768/49152
  const int tid = threadIdx.x, lane = tid & 63, wave = tid >> 6;
  const int l15 = lane & 15, l4 = lane >> 4;
  const int wr = wave & 3, wc = wave >> 2;  // 8 waves: 4x2 of 32x64
  // bijective XCD-chunked mb-major remap: 9728 = 8 * 1216
  const int bid = blockIdx.x;
  const int swz = (bid & 7) * 1216 + (bid >> 3);
  const int mb = swz / 19, nb = swz - mb * 19;
  const unsigned short* Ab = ws + OFF_XG + (size_t)mb * 128 * 384;
  const unsigned short* Bb =
      (nb < 18) ? ws + (size_t)nb * 128 * 384 : ws + OFF_WG;
  // per-lane source-swizzle offsets: row-in-8-group + swizzled col16
  const int lr = lane >> 3, lc = (lane & 7) ^ lr;
  const int offS = lr * 384 + lc * 8;
  f32x4 of[2][4] = {};

#define K1_STAGE(KS, BUF)                                                     \
  {                                                                           \
    _Pragma("unroll") for (int i = 0; i < 2; ++i) {                           \
      const int R = wave * 16 + i * 8;                                        \
      GLOAD(Ab + (size_t)R * 384 + (KS)*64 + offS, sm + (BUF) + R * 128);     \
      GLOAD(Bb + (size_t)R * 384 + (KS)*64 + offS,                            \
            sm + 32768 + (BUF) + R * 128);                                    \
    }                                                                         \
  }

  K1_STAGE(0, 0);
#pragma unroll 1
  for (int ks = 0; ks < 6; ++ks) {
    const int cur = (ks & 1) * 16384;
    if (ks + 1 < 6) K1_STAGE(ks + 1, 16384 - cur);
    __builtin_amdgcn_sched_barrier(0);
    if (ks + 1 < 6)
      asm volatile("s_waitcnt vmcnt(4)" ::: "memory");
    else
      asm volatile("s_waitcnt vmcnt(0)" ::: "memory");
    __builtin_amdgcn_sched_barrier(0);
    __builtin_amdgcn_s_barrier();  // tile ks resident
    __builtin_amdgcn_sched_barrier(0);
#pragma unroll
    for (int kk = 0; kk < 2; ++kk) {
      bf16x8 af[2], bfr[4];
#pragma unroll
      for (int mt = 0; mt < 2; ++mt) {
        int row = wr * 32 + mt * 16 + l15;
        af[mt] = *(const bf16x8*)(sm + cur +
                 ((row * 128 + kk * 64 + l4 * 16) ^ ((row & 7) << 4)));
      }
#pragma unroll
      for (int nt = 0; nt < 4; ++nt) {
        int row = wc * 64 + nt * 16 + l15;
        bfr[nt] = *(const bf16x8*)(sm + 32768 + cur +
                  ((row * 128 + kk * 64 + l4 * 16) ^ ((row & 7) << 4)));
      }
#pragma unroll
      for (int mt = 0; mt < 2; ++mt)
#pragma unroll
        for (int nt = 0; nt < 4; ++nt)
          of[mt][nt] = MFMA(af[mt], bfr[nt], of[mt][nt]);
    }
    kbar();  // LDS reads published; next STAGE may overwrite buf^1
  }
  // epilogue: accs -> LDS bf16 [128][256B] swz -> coalesced CACHEABLE store
  const float ssc = srs[0], sbi = srb[0];
  const bool ffreg = (nb >= 6) && (nb < 18);
#pragma unroll
  for (int mt = 0; mt < 2; ++mt)
#pragma unroll
    for (int nt = 0; nt < 4; ++nt)
#pragma unroll
      for (int rr = 0; rr < 4; ++rr) {
        int row = wr * 32 + mt * 16 + l4 * 4 + rr;
        int col = wc * 64 + nt * 16 + l15;
        float v = of[mt][nt][rr];
        if (ffreg) { v = fmaxf(v, 0.0f); v = ssc * v * v + sbi; }
        *(ushort_a*)(sm + ((row * 256 + col * 2) ^ ((row & 7) << 4))) = f2bf(v);
      }
  __syncthreads();
  if (nb < 18) {
    unsigned short* fo = ws + OFF_FUSED + (size_t)mb * 128 * 2304 + nb * 128;
#pragma unroll
    for (int r2 = 0; r2 < 4; ++r2) {
      int idx = r2 * 512 + tid;
      int row = idx >> 4, c = idx & 15;
      int byte = (row * 256 + c * 16) ^ ((row & 7) << 4);
      *(us8*)(fo + (size_t)row * 2304 + c * 8) = *(us8*)(sm + byte);
    }
  } else {
    unsigned short* go = ws + OFF_GATE + (size_t)mb * 128 * 16;
#pragma unroll
    for (int r2 = 0; r2 < 4; ++r2) {
      int idx = r2 * 512 + tid;
      int row = idx >> 4, c = idx & 15;
      if (c < 2) {
        int byte = (row * 256 + c * 16) ^ ((row & 7) << 4);
        *(us8*)(go + (size_t)row * 16 + c * 8) = *(us8*)(sm + byte);
      }
    }
  }
}

// ---- k2: windowed attention (per-wave private, no barriers) ----
__global__ __launch_bounds__(256, 3) void k2_attn(unsigned short* __restrict__ ws,
                                                  const float* __restrict__ bgate) {
  __shared__ __align__(16) char sm[49152];
  const int tid = threadIdx.x, lane = tid & 63, wave = tid >> 6;
  const int l15 = lane & 15, l4 = lane >> 4;
  char* kvT = sm + wave * 12288;  // [32 d][128B m]
  char* Pb = kvT + 4096;          // [64 n][128B m]
  const int wi = blockIdx.x;
  const size_t T0 = (size_t)wi * 64;
  unsigned short* fused = ws + OFF_FUSED;
  const unsigned short* gb = ws + OFF_GATE;
  const f32x4 zz = {};
#pragma unroll 1
  for (int hi = 0; hi < 3; ++hi) {
    const int h = wave + hi * 4;
    bf16x8 akv[4], bq[4];
#pragma unroll
    for (int t = 0; t < 4; ++t) {
      akv[t] = *(const bf16x8*)(fused + (T0 + t * 16 + l15) * 2304 + 384 + h * 32 + l4 * 8);
      bq[t] = *(const bf16x8*)(fused + (T0 + t * 16 + l15) * 2304 + h * 32 + l4 * 8);
    }
    f32x4 sfT[4][4];
#pragma unroll
    for (int mt = 0; mt < 4; ++mt)
#pragma unroll
      for (int ni = 0; ni < 4; ++ni) sfT[mt][ni] = MFMA(akv[mt], bq[ni], zz);
#pragma unroll
    for (int mt = 0; mt < 4; ++mt) {
      us8 u = __builtin_bit_cast(us8, akv[mt]);
      int m = mt * 16 + l15;
#pragma unroll
      for (int j = 0; j < 8; ++j) {
        int d = l4 * 8 + j;
        *(ushort_a*)(kvT + ((d * 128 + m * 2) ^ ((d & 7) << 4))) = u[j];
      }
    }
#pragma unroll
    for (int ni = 0; ni < 4; ++ni) {
      float s[16];
#pragma unroll
      for (int mt = 0; mt < 4; ++mt)
#pragma unroll
        for (int rr = 0; rr < 4; ++rr)
          s[mt * 4 + rr] = sfT[mt][ni][rr] * 0.176776695f;
      float mx = s[0];
#pragma unroll
      for (int q2 = 1; q2 < 16; ++q2) mx = fmaxf(mx, s[q2]);
      mx = fmaxf(mx, __shfl_xor(mx, 16, 64));
      mx = fmaxf(mx, __shfl_xor(mx, 32, 64));
      float sum = 0.0f;
#pragma unroll
      for (int q2 = 0; q2 < 16; ++q2) {
        s[q2] = __expf(s[q2] - mx);
        sum += s[q2];
      }
      sum += __shfl_xor(sum, 16, 64);
      sum += __shfl_xor(sum, 32, 64);
      float rs = 1.0f / sum;
      int n = ni * 16 + l15;
      int rowb = n * 128, sw = (n & 7) << 4;
#pragma unroll
      for (int mt = 0; mt < 4; ++mt) {
        int m = mt * 16 + l4 * 4;
        unsigned p0 = (unsigned)f2bf(s[mt * 4 + 0] * rs) |
                      ((unsigned)f2bf(s[mt * 4 + 1] * rs) << 16);
        unsigned p1 = (unsigned)f2bf(s[mt * 4 + 2] * rs) |
                      ((unsigned)f2bf(s[mt * 4 + 3] * rs) << 16);
        *(uint_a*)(Pb + ((rowb + m * 2) ^ sw)) = p0;
        *(uint_a*)(Pb + ((rowb + (m + 2) * 2) ^ sw)) = p1;
      }
    }
    f32x4 xo[4][2] = {};
#pragma unroll
    for (int ks = 0; ks < 2; ++ks) {
      bf16x8 bv[2];
#pragma unroll
      for (int dt = 0; dt < 2; ++dt) {
        int d = dt * 16 + l15;
        bv[dt] = *(const bf16x8*)(kvT + ((d * 128 + ks * 64 + l4 * 16) ^ ((d & 7) << 4)));
      }
#pragma unroll
      for (int nt = 0; nt < 4; ++nt) {
        int n = nt * 16 + l15;
        bf16x8 ap = *(const bf16x8*)(Pb + ((n * 128 + ks * 64 + l4 * 16) ^ ((n & 7) << 4)));
        xo[nt][0] = MFMA(ap, bv[0], xo[nt][0]);
        xo[nt][1] = MFMA(ap, bv[1], xo[nt][1]);
      }
    }
    const float bgh = bgate[h];
#pragma unroll
    for (int nt = 0; nt < 4; ++nt)
#pragma unroll
      for (int rr = 0; rr < 4; ++rr) {
        int n = nt * 16 + l4 * 4 + rr;
        float gv = bf2f(gb[(T0 + n) * 16 + h]) + bgh;
        float sg = 1.0f / (1.0f + __expf(-gv));
#pragma unroll
        for (int dt = 0; dt < 2; ++dt)
          fused[(T0 + n) * 2304 + h * 32 + dt * 16 + l15] =
              f2bf(xo[nt][dt][rr] * sg);
      }
  }
}

// ---- k3: out = Xattn . wao^T + F . wfo^T  (K=1920, NCHW epilogue) ----
// gload_lds + double buffer + counted vmcnt(8); mb reversed for L3 freshness.
__global__ __launch_bounds__(256, 2) void k3_gemm(const unsigned short* __restrict__ ws,
                                                  float* __restrict__ out) {
  __shared__ __align__(1024) char sm[65536];  // A: 0/16384; B: 32768/49152
  const int tid = threadIdx.x, lane = tid & 63, wave = tid >> 6;
  const int l15 = lane & 15, l4 = lane >> 4;
  const int wr = wave & 1, wc = wave >> 1;  // 2x2 waves of 64x64
  // bijective XCD-chunked mb-major remap (reversed): 1536 = 8 * 192
  const int bid = blockIdx.x;
  const int swz = (bid & 7) * 192 + (bid >> 3);
  const int mb = 511 - swz / 3, nB = swz % 3;
  const size_t T0 = (size_t)mb * 128;
  const unsigned short* fA = ws + OFF_FUSED + T0 * 2304;
  const unsigned short* wao = ws + OFF_WAO + (size_t)(nB * 128) * 384;
  const unsigned short* wfo = ws + OFF_WFO + (size_t)(nB * 128) * 1536;
  // per-lane source-swizzle offsets: row-in-8-group + swizzled col16
  const int lr = lane >> 3, lc = (lane & 7) ^ lr;
  const int offA = lr * 2304 + lc * 8;
  const int offB384 = lr * 384 + lc * 8;
  const int offB1536 = lr * 1536 + lc * 8;
  f32x4 of[4][4] = {};

#define K3_STAGE(KS, BUF)                                                     \
  {                                                                           \
    const int ac_ = (KS) < 6 ? (KS)*64 : 768 + ((KS)-6) * 64;                 \
    _Pragma("unroll") for (int i = 0; i < 4; ++i) {                           \
      const int R = wave * 32 + i * 8;                                        \
      GLOAD(fA + (size_t)R * 2304 + ac_ + offA, sm + (BUF) + R * 128);        \
      if ((KS) < 6)                                                           \
        GLOAD(wao + (size_t)R * 384 + (KS)*64 + offB384,                      \
              sm + 32768 + (BUF) + R * 128);                                  \
      else                                                                    \
        GLOAD(wfo + (size_t)R * 1536 + ((KS)-6) * 64 + offB1536,              \
              sm + 32768 + (BUF) + R * 128);                                  \
    }                                                                         \
  }

  K3_STAGE(0, 0);
#pragma unroll 1
  for (int ks = 0; ks < 30; ++ks) {
    const int cur = (ks & 1) * 16384;
    if (ks + 1 < 30) K3_STAGE(ks + 1, 16384 - cur);
    __builtin_amdgcn_sched_barrier(0);
    if (ks + 1 < 30)
      asm volatile("s_waitcnt vmcnt(8)" ::: "memory");
    else
      asm volatile("s_waitcnt vmcnt(0)" ::: "memory");
    __builtin_amdgcn_sched_barrier(0);
    __builtin_amdgcn_s_barrier();  // all waves waited own tile-ks loads
    __builtin_amdgcn_sched_barrier(0);
#pragma unroll
    for (int kk = 0; kk < 2; ++kk) {
      bf16x8 af[4], bfr[4];
#pragma unroll
      for (int mt = 0; mt < 4; ++mt) {
        int row = wr * 64 + mt * 16 + l15;
        af[mt] = *(const bf16x8*)(sm + cur +
                 ((row * 128 + kk * 64 + l4 * 16) ^ ((row & 7) << 4)));
      }
#pragma unroll
      for (int nt = 0; nt < 4; ++nt) {
        int row = wc * 64 + nt * 16 + l15;
        bfr[nt] = *(const bf16x8*)(sm + 32768 + cur +
                  ((row * 128 + kk * 64 + l4 * 16) ^ ((row & 7) << 4)));
      }
#pragma unroll
      for (int mt = 0; mt < 4; ++mt)
#pragma unroll
        for (int nt = 0; nt < 4; ++nt)
          of[mt][nt] = MFMA(af[mt], bfr[nt], of[mt][nt]);
    }
    kbar();  // LDS reads published; next STAGE may overwrite buf^1
  }
  // epilogue: NCHW fp32 NT scatter (out is never re-read)
#pragma unroll
  for (int mt = 0; mt < 4; ++mt) {
    int n0 = wr * 64 + mt * 16 + l4 * 4;
    int T = (int)T0 + n0;
    int wi = T >> 6, n = T & 63;
    int b = wi >> 6, ghi = (wi >> 3) & 7, gwi = wi & 7;
    float* ob = out + (size_t)b * 1572864 + (size_t)(ghi * 8 + (n >> 3)) * 64 +
                gwi * 8 + (n & 7);
#pragma unroll
    for (int nt = 0; nt < 4; ++nt) {
      int c = nB * 128 + wc * 64 + nt * 16 + l15;
      __builtin_nontemporal_store(of[mt][nt], (f32x4*)(ob + (size_t)c * 4096));
    }
  }
}

extern "C" void kernel_launch(void* const* d_in, const int* in_sizes, int n_in,
                              void* d_out, int out_size, void* d_ws, size_t ws_size,
                              hipStream_t stream) {
  const float* x = (const float*)d_in[0];
  const float* wf = (const float*)d_in[1];
  const float* wg = (const float*)d_in[2];
  const float* bg = (const float*)d_in[3];
  const float* wao = (const float*)d_in[4];
  const float* wfo = (const float*)d_in[5];
  const float* srs = (const float*)d_in[6];
  const float* srb = (const float*)d_in[7];
  unsigned short* ws = (unsigned short*)d_ws;

  prep_weights<<<6528, 256, 0, stream>>>(wf, wg, wao, wfo, ws);
  k0_gather<<<1024, 256, 0, stream>>>(x, ws + OFF_XG);
  k1_gemm<<<512 * 19, 512, 0, stream>>>(ws, srs, srb);
  k2_attn<<<1024, 256, 0, stream>>>(ws, bg);
  k3_gemm<<<512 * 3, 256, 0, stream>>>(ws, (float*)d_out);
}

// Round 21
// 467.808 us; speedup vs baseline: 1.0468x; 1.0468x over previous
//
#include <hip/hip_runtime.h>
#include <hip/hip_bf16.h>

// ---- types ----
typedef __bf16 bf16x8 __attribute__((ext_vector_type(8), may_alias));
typedef float f32x4 __attribute__((ext_vector_type(4), may_alias));
typedef unsigned short ushort_a __attribute__((may_alias));
typedef unsigned int uint_a __attribute__((may_alias));
typedef unsigned short us8 __attribute__((ext_vector_type(8), may_alias));

#define MFMA(a, b, c) __builtin_amdgcn_mfma_f32_16x16x32_bf16(a, b, c, 0, 0, 0)

__device__ __forceinline__ unsigned short f2bf(float f) {
  return __builtin_bit_cast(unsigned short, (__bf16)f);
}
__device__ __forceinline__ float bf2f(unsigned short u) {
  unsigned v = ((unsigned)u) << 16;
  return __builtin_bit_cast(float, v);
}

// Counted-vmcnt barrier (T4): publish own LDS ops, sync, leave global
// prefetch loads in flight (no vmcnt(0) drain).
__device__ __forceinline__ void kbar() {
  __builtin_amdgcn_sched_barrier(0);
  asm volatile("s_waitcnt lgkmcnt(0)" ::: "memory");
  __builtin_amdgcn_sched_barrier(0);
  __builtin_amdgcn_s_barrier();
  __builtin_amdgcn_sched_barrier(0);
}

// async global->LDS, 16B per lane; dest = wave-uniform base + lane*16
#define GLOAD(G, L)                                                          \
  __builtin_amdgcn_global_load_lds(                                          \
      (const __attribute__((address_space(1))) unsigned int*)(G),            \
      (__attribute__((address_space(3))) unsigned int*)(L), 16, 0, 0)

// ws layout (ushort elements):
//   wfB  [2304][384] @ 0
//   wgB  [128][384]  @ 884736    (rows >=12 zero)
//   waoB [384][384]  @ 933888
//   wfoB [384][1536] @ 1081344
//   xg   [65536][384]  @ 1671168
//   fused[65536][2304] @ 26836992  (q | kv | StarReLU(ff)); q overwritten by x_attn
//   gate [65536][16]   @ 177831936
#define OFF_WG 884736
#define OFF_WAO 933888
#define OFF_WFO 1081344
#define OFF_XG 1671168
#define OFF_FUSED 26836992
#define OFF_GATE 177831936

__global__ __launch_bounds__(256) void prep_weights(
    const float* __restrict__ wf, const float* __restrict__ wg,
    const float* __restrict__ wao, const float* __restrict__ wfo,
    unsigned short* __restrict__ ws) {
  int i = blockIdx.x * 256 + threadIdx.x;
  if (i < 884736) { ws[i] = f2bf(wf[i]); return; }
  int j = i - 884736;
  if (j < 49152) { ws[i] = f2bf(j < 4608 ? wg[j] : 0.0f); return; }
  j -= 49152;
  if (j < 147456) { ws[i] = f2bf(wao[j]); return; }
  j -= 147456;
  if (j < 589824) ws[i] = f2bf(wfo[j]);
}

// ---- k0: gather NCHW fp32 -> token-major bf16 xg [65536][384] ----
__global__ __launch_bounds__(256) void k0_gather(const float* __restrict__ x,
                                                 unsigned short* __restrict__ xg) {
  __shared__ __align__(16) char As[49152];
  int tid = threadIdx.x, wi = blockIdx.x;
  int b = wi >> 6, ghi = (wi >> 3) & 7, gwi = wi & 7;
  const float* xb = x + (size_t)b * 1572864 + (ghi * 8) * 64 + gwi * 8;
  for (int it = 0; it < 12; ++it) {
    int idx = it * 256 + tid;  // (c, p1)
    int c = idx % 384, p1 = idx / 384;
    const float* src = xb + (size_t)c * 4096 + p1 * 64;
    float4 v0 = *(const float4*)src, v1 = *(const float4*)(src + 4);
    float f[8] = {v0.x, v0.y, v0.z, v0.w, v1.x, v1.y, v1.z, v1.w};
#pragma unroll
    for (int jj = 0; jj < 8; ++jj) {
      int row = p1 * 8 + jj;
      int byte = (row * 768 + c * 2) ^ ((row & 7) << 4);
      *(ushort_a*)(As + byte) = f2bf(f[jj]);
    }
  }
  __syncthreads();
  unsigned short* og = xg + (size_t)wi * 24576;
#pragma unroll
  for (int it = 0; it < 12; ++it) {
    int idx = it * 256 + tid;
    int row = idx / 48, c = idx % 48;
    int byte = (row * 768 + c * 16) ^ ((row & 7) << 4);
    *(us8*)(og + (size_t)row * 384 + c * 8) = *(us8*)(As + byte);
  }
}

// ---- k1: fused = xg . W_fused^T  (M=65536, N=2304 + gate 16, K=384) ----
// gload_lds double-buffer + counted vmcnt(4) (r20's k1 gain) + NT epilogue
// stores (r16's fastest epilogue).
__global__ __launch_bounds__(512, 2) void k1_gemm(unsigned short* __restrict__ ws,
                                                  const float* __restrict__ srs,
                                                  const float* __restrict__ srb) {
  __shared__ __align__(1024) char sm[65536];  // A: 0/16384; B: 32768/49152
  const int tid = threadIdx.x, lane = tid & 63, wave = tid >> 6;
  const int l15 = lane & 15, l4 = lane >> 4;
  const int wr = wave & 3, wc = wave >> 2;  // 8 waves: 4x2 of 32x64
  // bijective XCD-chunked mb-major remap: 9728 = 8 * 1216
  const int bid = blockIdx.x;
  const int swz = (bid & 7) * 1216 + (bid >> 3);
  const int mb = swz / 19, nb = swz - mb * 19;
  const unsigned short* Ab = ws + OFF_XG + (size_t)mb * 128 * 384;
  const unsigned short* Bb =
      (nb < 18) ? ws + (size_t)nb * 128 * 384 : ws + OFF_WG;
  // per-lane source-swizzle offsets: row-in-8-group + swizzled col16
  const int lr = lane >> 3, lc = (lane & 7) ^ lr;
  const int offS = lr * 384 + lc * 8;
  f32x4 of[2][4] = {};

#define K1_STAGE(KS, BUF)                                                     \
  {                                                                           \
    _Pragma("unroll") for (int i = 0; i < 2; ++i) {                           \
      const int R = wave * 16 + i * 8;                                        \
      GLOAD(Ab + (size_t)R * 384 + (KS)*64 + offS, sm + (BUF) + R * 128);     \
      GLOAD(Bb + (size_t)R * 384 + (KS)*64 + offS,                            \
            sm + 32768 + (BUF) + R * 128);                                    \
    }                                                                         \
  }

  K1_STAGE(0, 0);
#pragma unroll 1
  for (int ks = 0; ks < 6; ++ks) {
    const int cur = (ks & 1) * 16384;
    if (ks + 1 < 6) K1_STAGE(ks + 1, 16384 - cur);
    __builtin_amdgcn_sched_barrier(0);
    if (ks + 1 < 6)
      asm volatile("s_waitcnt vmcnt(4)" ::: "memory");
    else
      asm volatile("s_waitcnt vmcnt(0)" ::: "memory");
    __builtin_amdgcn_sched_barrier(0);
    __builtin_amdgcn_s_barrier();  // tile ks resident
    __builtin_amdgcn_sched_barrier(0);
#pragma unroll
    for (int kk = 0; kk < 2; ++kk) {
      bf16x8 af[2], bfr[4];
#pragma unroll
      for (int mt = 0; mt < 2; ++mt) {
        int row = wr * 32 + mt * 16 + l15;
        af[mt] = *(const bf16x8*)(sm + cur +
                 ((row * 128 + kk * 64 + l4 * 16) ^ ((row & 7) << 4)));
      }
#pragma unroll
      for (int nt = 0; nt < 4; ++nt) {
        int row = wc * 64 + nt * 16 + l15;
        bfr[nt] = *(const bf16x8*)(sm + 32768 + cur +
                  ((row * 128 + kk * 64 + l4 * 16) ^ ((row & 7) << 4)));
      }
#pragma unroll
      for (int mt = 0; mt < 2; ++mt)
#pragma unroll
        for (int nt = 0; nt < 4; ++nt)
          of[mt][nt] = MFMA(af[mt], bfr[nt], of[mt][nt]);
    }
    kbar();  // LDS reads published; next STAGE may overwrite buf^1
  }
  // epilogue: accs -> LDS bf16 [128][256B] swz -> coalesced NT global store
  const float ssc = srs[0], sbi = srb[0];
  const bool ffreg = (nb >= 6) && (nb < 18);
#pragma unroll
  for (int mt = 0; mt < 2; ++mt)
#pragma unroll
    for (int nt = 0; nt < 4; ++nt)
#pragma unroll
      for (int rr = 0; rr < 4; ++rr) {
        int row = wr * 32 + mt * 16 + l4 * 4 + rr;
        int col = wc * 64 + nt * 16 + l15;
        float v = of[mt][nt][rr];
        if (ffreg) { v = fmaxf(v, 0.0f); v = ssc * v * v + sbi; }
        *(ushort_a*)(sm + ((row * 256 + col * 2) ^ ((row & 7) << 4))) = f2bf(v);
      }
  __syncthreads();
  if (nb < 18) {
    unsigned short* fo = ws + OFF_FUSED + (size_t)mb * 128 * 2304 + nb * 128;
#pragma unroll
    for (int r2 = 0; r2 < 4; ++r2) {
      int idx = r2 * 512 + tid;
      int row = idx >> 4, c = idx & 15;
      int byte = (row * 256 + c * 16) ^ ((row & 7) << 4);
      __builtin_nontemporal_store(*(us8*)(sm + byte),
                                  (us8*)(fo + (size_t)row * 2304 + c * 8));
    }
  } else {
    unsigned short* go = ws + OFF_GATE + (size_t)mb * 128 * 16;
#pragma unroll
    for (int r2 = 0; r2 < 4; ++r2) {
      int idx = r2 * 512 + tid;
      int row = idx >> 4, c = idx & 15;
      if (c < 2) {
        int byte = (row * 256 + c * 16) ^ ((row & 7) << 4);
        __builtin_nontemporal_store(*(us8*)(sm + byte),
                                    (us8*)(go + (size_t)row * 16 + c * 8));
      }
    }
  }
}

// ---- k2: windowed attention (per-wave private, no barriers) ----
__global__ __launch_bounds__(256, 3) void k2_attn(unsigned short* __restrict__ ws,
                                                  const float* __restrict__ bgate) {
  __shared__ __align__(16) char sm[49152];
  const int tid = threadIdx.x, lane = tid & 63, wave = tid >> 6;
  const int l15 = lane & 15, l4 = lane >> 4;
  char* kvT = sm + wave * 12288;  // [32 d][128B m]
  char* Pb = kvT + 4096;          // [64 n][128B m]
  const int wi = blockIdx.x;
  const size_t T0 = (size_t)wi * 64;
  unsigned short* fused = ws + OFF_FUSED;
  const unsigned short* gb = ws + OFF_GATE;
  const f32x4 zz = {};
#pragma unroll 1
  for (int hi = 0; hi < 3; ++hi) {
    const int h = wave + hi * 4;
    bf16x8 akv[4], bq[4];
#pragma unroll
    for (int t = 0; t < 4; ++t) {
      akv[t] = *(const bf16x8*)(fused + (T0 + t * 16 + l15) * 2304 + 384 + h * 32 + l4 * 8);
      bq[t] = *(const bf16x8*)(fused + (T0 + t * 16 + l15) * 2304 + h * 32 + l4 * 8);
    }
    f32x4 sfT[4][4];
#pragma unroll
    for (int mt = 0; mt < 4; ++mt)
#pragma unroll
      for (int ni = 0; ni < 4; ++ni) sfT[mt][ni] = MFMA(akv[mt], bq[ni], zz);
#pragma unroll
    for (int mt = 0; mt < 4; ++mt) {
      us8 u = __builtin_bit_cast(us8, akv[mt]);
      int m = mt * 16 + l15;
#pragma unroll
      for (int j = 0; j < 8; ++j) {
        int d = l4 * 8 + j;
        *(ushort_a*)(kvT + ((d * 128 + m * 2) ^ ((d & 7) << 4))) = u[j];
      }
    }
#pragma unroll
    for (int ni = 0; ni < 4; ++ni) {
      float s[16];
#pragma unroll
      for (int mt = 0; mt < 4; ++mt)
#pragma unroll
        for (int rr = 0; rr < 4; ++rr)
          s[mt * 4 + rr] = sfT[mt][ni][rr] * 0.176776695f;
      float mx = s[0];
#pragma unroll
      for (int q2 = 1; q2 < 16; ++q2) mx = fmaxf(mx, s[q2]);
      mx = fmaxf(mx, __shfl_xor(mx, 16, 64));
      mx = fmaxf(mx, __shfl_xor(mx, 32, 64));
      float sum = 0.0f;
#pragma unroll
      for (int q2 = 0; q2 < 16; ++q2) {
        s[q2] = __expf(s[q2] - mx);
        sum += s[q2];
      }
      sum += __shfl_xor(sum, 16, 64);
      sum += __shfl_xor(sum, 32, 64);
      float rs = 1.0f / sum;
      int n = ni * 16 + l15;
      int rowb = n * 128, sw = (n & 7) << 4;
#pragma unroll
      for (int mt = 0; mt < 4; ++mt) {
        int m = mt * 16 + l4 * 4;
        unsigned p0 = (unsigned)f2bf(s[mt * 4 + 0] * rs) |
                      ((unsigned)f2bf(s[mt * 4 + 1] * rs) << 16);
        unsigned p1 = (unsigned)f2bf(s[mt * 4 + 2] * rs) |
                      ((unsigned)f2bf(s[mt * 4 + 3] * rs) << 16);
        *(uint_a*)(Pb + ((rowb + m * 2) ^ sw)) = p0;
        *(uint_a*)(Pb + ((rowb + (m + 2) * 2) ^ sw)) = p1;
      }
    }
    f32x4 xo[4][2] = {};
#pragma unroll
    for (int ks = 0; ks < 2; ++ks) {
      bf16x8 bv[2];
#pragma unroll
      for (int dt = 0; dt < 2; ++dt) {
        int d = dt * 16 + l15;
        bv[dt] = *(const bf16x8*)(kvT + ((d * 128 + ks * 64 + l4 * 16) ^ ((d & 7) << 4)));
      }
#pragma unroll
      for (int nt = 0; nt < 4; ++nt) {
        int n = nt * 16 + l15;
        bf16x8 ap = *(const bf16x8*)(Pb + ((n * 128 + ks * 64 + l4 * 16) ^ ((n & 7) << 4)));
        xo[nt][0] = MFMA(ap, bv[0], xo[nt][0]);
        xo[nt][1] = MFMA(ap, bv[1], xo[nt][1]);
      }
    }
    const float bgh = bgate[h];
#pragma unroll
    for (int nt = 0; nt < 4; ++nt)
#pragma unroll
      for (int rr = 0; rr < 4; ++rr) {
        int n = nt * 16 + l4 * 4 + rr;
        float gv = bf2f(gb[(T0 + n) * 16 + h]) + bgh;
        float sg = 1.0f / (1.0f + __expf(-gv));
#pragma unroll
        for (int dt = 0; dt < 2; ++dt)
          fused[(T0 + n) * 2304 + h * 32 + dt * 16 + l15] =
              f2bf(xo[nt][dt][rr] * sg);
      }
  }
}

// ---- k3: out = Xattn . wao^T + F . wfo^T  (K=1920, NCHW epilogue) ----
// gload_lds + double buffer + counted vmcnt(8) (r16 structure, best k3).
__global__ __launch_bounds__(256, 2) void k3_gemm(const unsigned short* __restrict__ ws,
                                                  float* __restrict__ out) {
  __shared__ __align__(1024) char sm[65536];  // A: 0/16384; B: 32768/49152
  const int tid = threadIdx.x, lane = tid & 63, wave = tid >> 6;
  const int l15 = lane & 15, l4 = lane >> 4;
  const int wr = wave & 1, wc = wave >> 1;  // 2x2 waves of 64x64
  // bijective XCD-chunked mb-major remap: 1536 = 8 * 192
  const int bid = blockIdx.x;
  const int swz = (bid & 7) * 192 + (bid >> 3);
  const int mb = swz / 3, nB = swz - mb * 3;
  const size_t T0 = (size_t)mb * 128;
  const unsigned short* fA = ws + OFF_FUSED + T0 * 2304;
  const unsigned short* wao = ws + OFF_WAO + (size_t)(nB * 128) * 384;
  const unsigned short* wfo = ws + OFF_WFO + (size_t)(nB * 128) * 1536;
  // per-lane source-swizzle offsets: row-in-8-group + swizzled col16
  const int lr = lane >> 3, lc = (lane & 7) ^ lr;
  const int offA = lr * 2304 + lc * 8;
  const int offB384 = lr * 384 + lc * 8;
  const int offB1536 = lr * 1536 + lc * 8;
  f32x4 of[4][4] = {};

#define K3_STAGE(KS, BUF)                                                     \
  {                                                                           \
    const int ac_ = (KS) < 6 ? (KS)*64 : 768 + ((KS)-6) * 64;                 \
    _Pragma("unroll") for (int i = 0; i < 4; ++i) {                           \
      const int R = wave * 32 + i * 8;                                        \
      GLOAD(fA + (size_t)R * 2304 + ac_ + offA, sm + (BUF) + R * 128);        \
      if ((KS) < 6)                                                           \
        GLOAD(wao + (size_t)R * 384 + (KS)*64 + offB384,                      \
              sm + 32768 + (BUF) + R * 128);                                  \
      else                                                                    \
        GLOAD(wfo + (size_t)R * 1536 + ((KS)-6) * 64 + offB1536,              \
              sm + 32768 + (BUF) + R * 128);                                  \
    }                                                                         \
  }

  K3_STAGE(0, 0);
#pragma unroll 1
  for (int ks = 0; ks < 30; ++ks) {
    const int cur = (ks & 1) * 16384;
    if (ks + 1 < 30) K3_STAGE(ks + 1, 16384 - cur);
    __builtin_amdgcn_sched_barrier(0);
    if (ks + 1 < 30)
      asm volatile("s_waitcnt vmcnt(8)" ::: "memory");
    else
      asm volatile("s_waitcnt vmcnt(0)" ::: "memory");
    __builtin_amdgcn_sched_barrier(0);
    __builtin_amdgcn_s_barrier();  // all waves waited own tile-ks loads
    __builtin_amdgcn_sched_barrier(0);
#pragma unroll
    for (int kk = 0; kk < 2; ++kk) {
      bf16x8 af[4], bfr[4];
#pragma unroll
      for (int mt = 0; mt < 4; ++mt) {
        int row = wr * 64 + mt * 16 + l15;
        af[mt] = *(const bf16x8*)(sm + cur +
                 ((row * 128 + kk * 64 + l4 * 16) ^ ((row & 7) << 4)));
      }
#pragma unroll
      for (int nt = 0; nt < 4; ++nt) {
        int row = wc * 64 + nt * 16 + l15;
        bfr[nt] = *(const bf16x8*)(sm + 32768 + cur +
                  ((row * 128 + kk * 64 + l4 * 16) ^ ((row & 7) << 4)));
      }
#pragma unroll
      for (int mt = 0; mt < 4; ++mt)
#pragma unroll
        for (int nt = 0; nt < 4; ++nt)
          of[mt][nt] = MFMA(af[mt], bfr[nt], of[mt][nt]);
    }
    kbar();  // LDS reads published; next STAGE may overwrite buf^1
  }
  // epilogue: NCHW fp32 NT scatter (out is never re-read)
#pragma unroll
  for (int mt = 0; mt < 4; ++mt) {
    int n0 = wr * 64 + mt * 16 + l4 * 4;
    int T = (int)T0 + n0;
    int wi = T >> 6, n = T & 63;
    int b = wi >> 6, ghi = (wi >> 3) & 7, gwi = wi & 7;
    float* ob = out + (size_t)b * 1572864 + (size_t)(ghi * 8 + (n >> 3)) * 64 +
                gwi * 8 + (n & 7);
#pragma unroll
    for (int nt = 0; nt < 4; ++nt) {
      int c = nB * 128 + wc * 64 + nt * 16 + l15;
      __builtin_nontemporal_store(of[mt][nt], (f32x4*)(ob + (size_t)c * 4096));
    }
  }
}

extern "C" void kernel_launch(void* const* d_in, const int* in_sizes, int n_in,
                              void* d_out, int out_size, void* d_ws, size_t ws_size,
                              hipStream_t stream) {
  const float* x = (const float*)d_in[0];
  const float* wf = (const float*)d_in[1];
  const float* wg = (const float*)d_in[2];
  const float* bg = (const float*)d_in[3];
  const float* wao = (const float*)d_in[4];
  const float* wfo = (const float*)d_in[5];
  const float* srs = (const float*)d_in[6];
  const float* srb = (const float*)d_in[7];
  unsigned short* ws = (unsigned short*)d_ws;

  prep_weights<<<6528, 256, 0, stream>>>(wf, wg, wao, wfo, ws);
  k0_gather<<<1024, 256, 0, stream>>>(x, ws + OFF_XG);
  k1_gemm<<<512 * 19, 512, 0, stream>>>(ws, srs, srb);
  k2_attn<<<1024, 256, 0, stream>>>(ws, bg);
  k3_gemm<<<512 * 3, 256, 0, stream>>>(ws, (float*)d_out);
}